// Round 7
// baseline (540.244 us; speedup 1.0000x reference)
//
#include <hip/hip_runtime.h>

// Problem constants
#define BB  2
#define SS  2048
#define DD  2048
#define HH  16
#define HDD 128
#define BSR 4096   // BB*SS rows

using short8  = __attribute__((ext_vector_type(8))) short;
using floatx4 = __attribute__((ext_vector_type(4))) float;

__device__ __forceinline__ float bf2f(unsigned short u) {
  return __uint_as_float(((unsigned int)u) << 16);
}
__device__ __forceinline__ unsigned short f2bf(float f) {
  unsigned int u = __float_as_uint(f);
  u += 0x7fffu + ((u >> 16) & 1u);   // round-to-nearest-even
  return (unsigned short)(u >> 16);
}
// pack two floats -> two bf16 (rne) in one u32 (a=low, b=high)
__device__ __forceinline__ unsigned int pk2bf(float a, float b) {
  unsigned int ua = __float_as_uint(a);
  ua += 0x7fffu + ((ua >> 16) & 1u);
  unsigned int ub = __float_as_uint(b);
  ub += 0x7fffu + ((ub >> 16) & 1u);
  return (ua >> 16) | (ub & 0xffff0000u);
}
// fast 2^x (scores are kept in log2 domain)
__device__ __forceinline__ float fexp2(float x) {
#if __has_builtin(__builtin_amdgcn_exp2f)
  return __builtin_amdgcn_exp2f(x);
#else
  return __expf(x * 0.6931471805599453f);
#endif
}
// async global->LDS, 16 bytes per lane. LDS dest must be wave-uniform base + lane*16.
__device__ __forceinline__ void gl_lds16(const void* g, void* l) {
  __builtin_amdgcn_global_load_lds(
      (__attribute__((address_space(1))) void*)g,
      (__attribute__((address_space(3))) void*)l, 16, 0, 0);
}

// ---------------- fused prep: weight transpose (4096 blk, 64x64 f4-vectorized)
// ---------------- + x->bf16 (8192 blk) + RoPE table (512 blk), one dispatch ----
__global__ __launch_bounds__(256) void prep(
    const float* __restrict__ x,
    const float* __restrict__ Wq, const float* __restrict__ Wk,
    const float* __restrict__ Wv, const float* __restrict__ Wo,
    unsigned short* __restrict__ xb,
    unsigned short* __restrict__ wqkvt, unsigned short* __restrict__ wot,
    float2* __restrict__ rtab)
{
  __shared__ float tile[64][65];
  int bid = blockIdx.x;
  int t = threadIdx.x;
  if (bid < 4096) {
    // weight transpose + bf16 convert: Out[f][d] = W[d][f], 64x64 tile
    int z = bid >> 10;
    int rem = bid & 1023;
    int by = rem >> 5, bx = rem & 31;
    const float* W; unsigned short* Out;
    if      (z == 0) { W = Wq; Out = wqkvt; }
    else if (z == 1) { W = Wk; Out = wqkvt + (size_t)DD * DD; }
    else if (z == 2) { W = Wv; Out = wqkvt + 2 * (size_t)DD * DD; }
    else             { W = Wo; Out = wot; }
    int d0 = by * 64, f0 = bx * 64;
    int rr = t >> 4, c4 = (t & 15) * 4;
#pragma unroll
    for (int i = 0; i < 4; i++) {
      int row = rr + i * 16;
      float4 v = *(const float4*)&W[(size_t)(d0 + row) * DD + f0 + c4];
      tile[row][c4] = v.x; tile[row][c4 + 1] = v.y;
      tile[row][c4 + 2] = v.z; tile[row][c4 + 3] = v.w;
    }
    __syncthreads();
#pragma unroll
    for (int i = 0; i < 4; i++) {
      int f = rr + i * 16;
      ushort4 o4;
      o4.x = f2bf(tile[c4][f]);     o4.y = f2bf(tile[c4 + 1][f]);
      o4.z = f2bf(tile[c4 + 2][f]); o4.w = f2bf(tile[c4 + 3][f]);
      *(ushort4*)&Out[(size_t)(f0 + f) * DD + d0 + c4] = o4;
    }
  } else if (bid < 4096 + 8192) {
    // x -> bf16
    size_t i = ((size_t)(bid - 4096) * 256 + t) * 4;
    float4 v = *(const float4*)(x + i);
    ushort4 o;
    o.x = f2bf(v.x); o.y = f2bf(v.y); o.z = f2bf(v.z); o.w = f2bf(v.w);
    *(ushort4*)(xb + i) = o;
  } else {
    // RoPE cos/sin table: rtab[s][c] = (cos, sin), s<2048, c<64
    int idx = (bid - 12288) * 256 + t;
    int s = idx >> 6, c = idx & 63;
    float inv = powf(10000.f, -(float)c * (1.f / 64.f));
    float ang = (float)s * inv;
    float sn, cc;
    sincosf(ang, &sn, &cc);
    rtab[idx] = make_float2(cc, sn);
  }
}

// ---------------- fused QKV GEMM + bias + RoPE + V-transpose (proven 123 µs) ----
// C[4096,6144] = xb * wqkvt^T. 128x128 tile == exactly one (plane, head) column
// block. Epilogue round-trips the tile through LDS (stride 132 = +4 pad) and
// writes q_r/k_r (bias+RoPE, q prescaled by 1/sqrt(HD)*log2e) or v_t
// (bias + [hd][s] transpose with kappa key-permute) directly.
__global__ __launch_bounds__(256) void gemm_qkv(
    const unsigned short* __restrict__ A, const unsigned short* __restrict__ Bt,
    const float* __restrict__ bq, const float* __restrict__ bk,
    const float* __restrict__ bv, const float2* __restrict__ rtab,
    unsigned short* __restrict__ q_r, unsigned short* __restrict__ k_r,
    unsigned short* __restrict__ v_t)
{
  __shared__ unsigned short smem[16896];   // As(8192)|Bs(8192); reused as Ct[128][132]
  unsigned short* As = smem;
  unsigned short* Bs = smem + 8192;
  const int K = DD;
  int t = threadIdx.x;
  int m0 = blockIdx.y * 128, n0 = blockIdx.x * 128;
  int w = t >> 6, lane = t & 63, qd = lane >> 4, l16 = lane & 15;
  int wm = (w >> 1) * 64, wn = (w & 1) * 64;
  floatx4 zero4 = {0.f, 0.f, 0.f, 0.f};
  floatx4 acc[4][4];
#pragma unroll
  for (int i = 0; i < 4; i++)
#pragma unroll
    for (int j = 0; j < 4; j++) acc[i][j] = zero4;

  int gchunk = (t & 7) ^ ((t >> 3) & 7);
  const unsigned short* Ab = A  + (size_t)(m0 + (t >> 3)) * K + gchunk * 8;
  const unsigned short* Bb = Bt + (size_t)(n0 + (t >> 3)) * K + gchunk * 8;
  size_t qK = (size_t)32 * K;

  for (int k0 = 0; k0 < K; k0 += 64) {
    __syncthreads();
#pragma unroll
    for (int c = 0; c < 4; c++) {
      gl_lds16(Ab + c * qK + k0, &As[(c * 256 + t) * 8]);
      gl_lds16(Bb + c * qK + k0, &Bs[(c * 256 + t) * 8]);
    }
    __syncthreads();
#pragma unroll
    for (int ks = 0; ks < 2; ks++) {
      int ch = ((ks * 4 + qd) ^ (l16 & 7)) * 8;
      short8 af[4], bfr[4];
#pragma unroll
      for (int i = 0; i < 4; i++)
        af[i] = *(const short8*)&As[(wm + i * 16 + l16) * 64 + ch];
#pragma unroll
      for (int j = 0; j < 4; j++)
        bfr[j] = *(const short8*)&Bs[(wn + j * 16 + l16) * 64 + ch];
#pragma unroll
      for (int i = 0; i < 4; i++)
#pragma unroll
        for (int j = 0; j < 4; j++)
          acc[i][j] = __builtin_amdgcn_mfma_f32_16x16x32_bf16(af[i], bfr[j], acc[i][j], 0, 0, 0);
    }
  }

  // ---- epilogue ----
  int plane = n0 >> 11;            // 0=q, 1=k, 2=v
  int h = (n0 >> 7) & 15;
  const float* bias = plane == 0 ? bq : (plane == 1 ? bk : bv);
  __syncthreads();                 // all waves done reading As/Bs
#pragma unroll
  for (int i = 0; i < 4; i++)
#pragma unroll
    for (int j = 0; j < 4; j++) {
      int rl = wm + i * 16 + qd * 4;
      int cl = wn + j * 16 + l16;
      float bsv = bias[h * 128 + cl];
#pragma unroll
      for (int r = 0; r < 4; r++)
        smem[(rl + r) * 132 + cl] = f2bf(acc[i][j][r] + bsv);
    }
  __syncthreads();

  int b = m0 >> 11, sbase = m0 & (SS - 1);
  if (plane < 2) {
    unsigned short* dst = (plane == 0 ? q_r : k_r) + (size_t)(b * HH + h) * SS * HDD;
    // q prescale: 1/sqrt(128) * log2(e); k unscaled
    const float fac = (plane == 0) ? 0.12751744f : 1.0f;
#pragma unroll
    for (int it = 0; it < 16; it++) {
      int idx = it * 256 + t;
      int rl = idx >> 5, c2 = (idx & 31) * 2;
      int s = sbase + rl;
      float4 cs = *(const float4*)&rtab[(size_t)s * 64 + c2]; // cos0,sin0,cos1,sin1
      float a0 = bf2f(smem[rl * 132 + c2]);
      float a1 = bf2f(smem[rl * 132 + c2 + 1]);
      float b0 = bf2f(smem[rl * 132 + c2 + 64]);
      float b1 = bf2f(smem[rl * 132 + c2 + 65]);
      unsigned int lo = pk2bf((a0 * cs.x - b0 * cs.y) * fac,
                              (a1 * cs.z - b1 * cs.w) * fac);
      unsigned int hi = pk2bf((a0 * cs.y + b0 * cs.x) * fac,
                              (a1 * cs.w + b1 * cs.z) * fac);
      size_t rowb = (size_t)s * HDD;
      *(unsigned int*)&dst[rowb + c2]      = lo;
      *(unsigned int*)&dst[rowb + c2 + 64] = hi;
    }
  } else {
    // v: transpose to [hd][s] with kappa key-permute within each 64-block
    unsigned short* dst = v_t + (size_t)(b * HH + h) * HDD * SS;
#pragma unroll
    for (int it = 0; it < 32; it++) {
      int idx = it * 256 + t;
      int hd = idx >> 6, sp = (idx & 63) * 2;
      unsigned short v0 = smem[sp * 132 + hd];
      unsigned short v1 = smem[(sp + 1) * 132 + hd];
      int y = sp & 63;
      int kap = ((y >> 5) & 1) * 32 + ((y >> 2) & 3) * 8 + ((y >> 4) & 1) * 4 + (y & 3);
      int sg = sbase + (sp & ~63) + kap;
      *(unsigned int*)&dst[(size_t)hd * SS + sg] = ((unsigned int)v1 << 16) | v0;
    }
  }
}

// ---------------- bf16 MFMA GEMM, B^T layout, BK=64 (final projection) -----------
template <bool OUTF32>
__global__ __launch_bounds__(256) void gemm_bt(
    const unsigned short* __restrict__ A, const unsigned short* __restrict__ Bt,
    const float* __restrict__ bias, void* __restrict__ Cout,
    int M, int N, int K)
{
  __shared__ unsigned short As[128 * 64];
  __shared__ unsigned short Bs[128 * 64];
  int t = threadIdx.x;
  int m0 = blockIdx.y * 128, n0 = blockIdx.x * 128;
  int w = t >> 6, lane = t & 63, qd = lane >> 4, l16 = lane & 15;
  int wm = (w >> 1) * 64, wn = (w & 1) * 64;
  floatx4 zero4 = {0.f, 0.f, 0.f, 0.f};
  floatx4 acc[4][4];
#pragma unroll
  for (int i = 0; i < 4; i++)
#pragma unroll
    for (int j = 0; j < 4; j++) acc[i][j] = zero4;

  int gchunk = (t & 7) ^ ((t >> 3) & 7);
  const unsigned short* Ab = A  + (size_t)(m0 + (t >> 3)) * K + gchunk * 8;
  const unsigned short* Bb = Bt + (size_t)(n0 + (t >> 3)) * K + gchunk * 8;
  size_t qK = (size_t)32 * K;

  for (int k0 = 0; k0 < K; k0 += 64) {
    __syncthreads();
#pragma unroll
    for (int c = 0; c < 4; c++) {
      gl_lds16(Ab + c * qK + k0, &As[(c * 256 + t) * 8]);
      gl_lds16(Bb + c * qK + k0, &Bs[(c * 256 + t) * 8]);
    }
    __syncthreads();
#pragma unroll
    for (int ks = 0; ks < 2; ks++) {
      int ch = ((ks * 4 + qd) ^ (l16 & 7)) * 8;
      short8 af[4], bfr[4];
#pragma unroll
      for (int i = 0; i < 4; i++)
        af[i] = *(const short8*)&As[(wm + i * 16 + l16) * 64 + ch];
#pragma unroll
      for (int j = 0; j < 4; j++)
        bfr[j] = *(const short8*)&Bs[(wn + j * 16 + l16) * 64 + ch];
#pragma unroll
      for (int i = 0; i < 4; i++)
#pragma unroll
        for (int j = 0; j < 4; j++)
          acc[i][j] = __builtin_amdgcn_mfma_f32_16x16x32_bf16(af[i], bfr[j], acc[i][j], 0, 0, 0);
    }
  }

#pragma unroll
  for (int i = 0; i < 4; i++)
#pragma unroll
    for (int j = 0; j < 4; j++) {
      int row = m0 + wm + i * 16 + qd * 4;
      int col = n0 + wn + j * 16 + l16;
      float bsv = bias ? bias[col] : 0.f;
#pragma unroll
      for (int r = 0; r < 4; r++) {
        float v = acc[i][j][r] + bsv;
        if (OUTF32) ((float*)Cout)[(size_t)(row + r) * N + col] = v;
        else ((unsigned short*)Cout)[(size_t)(row + r) * N + col] = f2bf(v);
      }
    }
}

// ---------------- flash attention v6: LDS-free, direct L1/L2 streaming ----------
// K/V per head = 1 MB, L2-resident (XCD swizzle pins a head's 16 q-blocks to one
// XCD); all 4 waves of a block read the same 32 KB/tile -> L1 absorbs the reuse.
// The old LDS staging was a pure pass-through (stage swizzle ^ read swizzle
// cancel), so fragments are loaded directly:
//   kf = kb[(kt+krow)*HDD + chunk*8],  av = vb[vrow*SS + kt + chunk*8]
// No __syncthreads in the loop, no LDS -> waves stream independently; VMEM
// latency hidden by TLP (2 blocks/CU) + MFMA overlap.
__global__ __launch_bounds__(256, 2) void attn_kernel(
    const unsigned short* __restrict__ q_r, const unsigned short* __restrict__ k_r,
    const unsigned short* __restrict__ v_t, unsigned short* __restrict__ aout)
{
  int t = threadIdx.x, w = t >> 6, lane = t & 63, qd = lane >> 4, l16 = lane & 15;
  // XCD-aware remap: all 16 q-tiles of one head land on one XCD
  int L = blockIdx.y * gridDim.x + blockIdx.x;
  int jj = L >> 3;
  int bh = (L & 7) * 4 + (jj >> 4);
  int q0 = (jj & 15) * 128;
  const unsigned short* qb = q_r + (size_t)bh * SS * HDD;
  const unsigned short* kb = k_r + (size_t)bh * SS * HDD;
  const unsigned short* vb = v_t + (size_t)bh * HDD * SS;

  short8 aq[2][4];
#pragma unroll
  for (int mi = 0; mi < 2; mi++)
#pragma unroll
    for (int ks = 0; ks < 4; ks++)
      aq[mi][ks] = *(const short8*)
          &qb[(size_t)(q0 + w * 32 + mi * 16 + l16) * HDD + ks * 32 + qd * 8];

  float m_i[2], l_i[2];
  floatx4 zero4 = {0.f, 0.f, 0.f, 0.f};
  floatx4 o[2][8];   // O^T: rows hd (8 blocks of 16), cols qrow (mi)
#pragma unroll
  for (int mi = 0; mi < 2; mi++) { m_i[mi] = -1e30f; l_i[mi] = 0.f; }
#pragma unroll
  for (int mi = 0; mi < 2; mi++)
#pragma unroll
    for (int n = 0; n < 8; n++) o[mi][n] = zero4;

#pragma unroll 1
  for (int kt = 0; kt < SS; kt += 64) {
    floatx4 sc[2][4];
#pragma unroll
    for (int mi = 0; mi < 2; mi++)
#pragma unroll
      for (int j = 0; j < 4; j++) sc[mi][j] = zero4;
    __builtin_amdgcn_s_setprio(1);
#pragma unroll
    for (int j = 0; j < 4; j++) {
      const unsigned short* kp = kb + (size_t)(kt + j * 16 + l16) * HDD + qd * 8;
#pragma unroll
      for (int ks = 0; ks < 4; ks++) {
        short8 kf = *(const short8*)(kp + ks * 32);
        sc[0][j] = __builtin_amdgcn_mfma_f32_16x16x32_bf16(kf, aq[0][ks], sc[0][j], 0, 0, 0);
        sc[1][j] = __builtin_amdgcn_mfma_f32_16x16x32_bf16(kf, aq[1][ks], sc[1][j], 0, 0, 0);
      }
    }
    __builtin_amdgcn_s_setprio(0);

    float rmax[2];
#pragma unroll
    for (int mi = 0; mi < 2; mi++) {
      float m = sc[mi][0][0];
#pragma unroll
      for (int j = 0; j < 4; j++)
#pragma unroll
        for (int r = 0; r < 4; r++) m = fmaxf(m, sc[mi][j][r]);
      m = fmaxf(m, __shfl_xor(m, 16, 64));
      m = fmaxf(m, __shfl_xor(m, 32, 64));
      rmax[mi] = m;
    }

    bool up = (rmax[0] > m_i[0]) || (rmax[1] > m_i[1]);
    if (__ballot(up) != 0ull) {
#pragma unroll
      for (int mi = 0; mi < 2; mi++) {
        float mn = fmaxf(m_i[mi], rmax[mi]);
        float a = fexp2(m_i[mi] - mn);
        m_i[mi] = mn;
        l_i[mi] *= a;
#pragma unroll
        for (int n = 0; n < 8; n++)
#pragma unroll
          for (int r = 0; r < 4; r++) o[mi][n][r] *= a;
      }
    }

    unsigned int pr[2][4][2];
#pragma unroll
    for (int mi = 0; mi < 2; mi++) {
      float s0 = 0.f;
#pragma unroll
      for (int j = 0; j < 4; j++) {
        float p0 = fexp2(sc[mi][j][0] - m_i[mi]);
        float p1 = fexp2(sc[mi][j][1] - m_i[mi]);
        float p2 = fexp2(sc[mi][j][2] - m_i[mi]);
        float p3 = fexp2(sc[mi][j][3] - m_i[mi]);
        s0 += (p0 + p1) + (p2 + p3);
        pr[mi][j][0] = pk2bf(p0, p1);
        pr[mi][j][1] = pk2bf(p2, p3);
      }
      s0 += __shfl_xor(s0, 16, 64);
      s0 += __shfl_xor(s0, 32, 64);
      l_i[mi] += s0;
    }

    __builtin_amdgcn_s_setprio(1);
#pragma unroll
    for (int n = 0; n < 8; n++) {
      const unsigned short* vp = vb + (size_t)(n * 16 + l16) * SS + kt + qd * 8;
#pragma unroll
      for (int ks = 0; ks < 2; ks++) {
        short8 av = *(const short8*)(vp + ks * 32);
        union { unsigned int u[4]; short8 v; } bp0, bp1;
        bp0.u[0] = pr[0][2 * ks][0];     bp0.u[1] = pr[0][2 * ks][1];
        bp0.u[2] = pr[0][2 * ks + 1][0]; bp0.u[3] = pr[0][2 * ks + 1][1];
        bp1.u[0] = pr[1][2 * ks][0];     bp1.u[1] = pr[1][2 * ks][1];
        bp1.u[2] = pr[1][2 * ks + 1][0]; bp1.u[3] = pr[1][2 * ks + 1][1];
        o[0][n] = __builtin_amdgcn_mfma_f32_16x16x32_bf16(av, bp0.v, o[0][n], 0, 0, 0);
        o[1][n] = __builtin_amdgcn_mfma_f32_16x16x32_bf16(av, bp1.v, o[1][n], 0, 0, 0);
      }
    }
    __builtin_amdgcn_s_setprio(0);
  }

  int b = bh >> 4, h = bh & 15;
#pragma unroll
  for (int mi = 0; mi < 2; mi++) {
    int qrow = q0 + w * 32 + mi * 16 + l16;
    float inv_l = 1.f / l_i[mi];
    size_t base = ((size_t)(b * SS + qrow)) * DD + h * HDD;
#pragma unroll
    for (int n = 0; n < 8; n++) {
      uint2 pkd;
      pkd.x = pk2bf(o[mi][n][0] * inv_l, o[mi][n][1] * inv_l);
      pkd.y = pk2bf(o[mi][n][2] * inv_l, o[mi][n][3] * inv_l);
      *(uint2*)&aout[base + n * 16 + qd * 4] = pkd;
    }
  }
}

// ---------------- launch ----------------
extern "C" void kernel_launch(void* const* d_in, const int* in_sizes, int n_in,
                              void* d_out, int out_size, void* d_ws, size_t ws_size,
                              hipStream_t stream) {
  const float* x  = (const float*)d_in[0];
  const float* Wq = (const float*)d_in[1];
  const float* bq = (const float*)d_in[2];
  const float* Wk = (const float*)d_in[3];
  const float* bk = (const float*)d_in[4];
  const float* Wv = (const float*)d_in[5];
  const float* bv = (const float*)d_in[6];
  const float* Wo = (const float*)d_in[7];
  const float* bo = (const float*)d_in[8];
  float* out = (float*)d_out;

  char* ws = (char*)d_ws;
  unsigned short* xb      = (unsigned short*)(ws + 0);            // [BS,D] bf16, 16 MB
  unsigned short* wqkvt   = (unsigned short*)(ws + 16777216);     // [3D,D] bf16, 24 MB
  unsigned short* wot     = (unsigned short*)(ws + 41943040);     // [D,D]  bf16, 8 MB
  float2*         rtab    = (float2*)(ws + 50331648);             // [S,64] f32x2, 1 MB
  unsigned short* q_r     = (unsigned short*)(ws + 100663296);    // [B,H,S,HD] 16 MB
  unsigned short* k_r     = (unsigned short*)(ws + 117440512);    // [B,H,S,HD] 16 MB
  unsigned short* v_t     = (unsigned short*)(ws + 134217728);    // [B,H,HD,S] 16 MB
  unsigned short* attn_o  = xb;   // alias: xb dead after gemm_qkv

  prep<<<dim3(12800), dim3(256), 0, stream>>>(
      x, Wq, Wk, Wv, Wo, xb, wqkvt, wot, rtab);
  gemm_qkv<<<dim3(3 * DD / 128, BSR / 128), dim3(256), 0, stream>>>(
      xb, wqkvt, bq, bk, bv, rtab, q_r, k_r, v_t);
  attn_kernel<<<dim3(SS / 128, BB * HH), dim3(256), 0, stream>>>(
      q_r, k_r, v_t, attn_o);
  gemm_bt<true><<<dim3(DD / 128, BSR / 128), dim3(256), 0, stream>>>(
      attn_o, wot, bo, out, BSR, DD, DD);
}

// Round 8
// 392.898 us; speedup vs baseline: 1.3750x; 1.3750x over previous
//
#include <hip/hip_runtime.h>

// Problem constants
#define BB  2
#define SS  2048
#define DD  2048
#define HH  16
#define HDD 128
#define BSR 4096   // BB*SS rows

using short8  = __attribute__((ext_vector_type(8))) short;
using floatx4 = __attribute__((ext_vector_type(4))) float;

__device__ __forceinline__ float bf2f(unsigned short u) {
  return __uint_as_float(((unsigned int)u) << 16);
}
__device__ __forceinline__ unsigned short f2bf(float f) {
  unsigned int u = __float_as_uint(f);
  u += 0x7fffu + ((u >> 16) & 1u);   // round-to-nearest-even
  return (unsigned short)(u >> 16);
}
// pack two floats -> two bf16 (rne) in one u32 (a=low, b=high)
__device__ __forceinline__ unsigned int pk2bf(float a, float b) {
  unsigned int ua = __float_as_uint(a);
  ua += 0x7fffu + ((ua >> 16) & 1u);
  unsigned int ub = __float_as_uint(b);
  ub += 0x7fffu + ((ub >> 16) & 1u);
  return (ua >> 16) | (ub & 0xffff0000u);
}
// fast 2^x (scores are kept in log2 domain)
__device__ __forceinline__ float fexp2(float x) {
#if __has_builtin(__builtin_amdgcn_exp2f)
  return __builtin_amdgcn_exp2f(x);
#else
  return __expf(x * 0.6931471805599453f);
#endif
}
// async global->LDS, 16 bytes per lane. LDS dest must be wave-uniform base + lane*16.
__device__ __forceinline__ void gl_lds16(const void* g, void* l) {
  __builtin_amdgcn_global_load_lds(
      (__attribute__((address_space(1))) void*)g,
      (__attribute__((address_space(3))) void*)l, 16, 0, 0);
}

// ---------------- fused prep: weight transpose (4096 blk, 64x64 f4-vectorized)
// ---------------- + x->bf16 (8192 blk) + RoPE table (512 blk), one dispatch ----
__global__ __launch_bounds__(256) void prep(
    const float* __restrict__ x,
    const float* __restrict__ Wq, const float* __restrict__ Wk,
    const float* __restrict__ Wv, const float* __restrict__ Wo,
    unsigned short* __restrict__ xb,
    unsigned short* __restrict__ wqkvt, unsigned short* __restrict__ wot,
    float2* __restrict__ rtab)
{
  __shared__ float tile[64][65];
  int bid = blockIdx.x;
  int t = threadIdx.x;
  if (bid < 4096) {
    // weight transpose + bf16 convert: Out[f][d] = W[d][f], 64x64 tile
    int z = bid >> 10;
    int rem = bid & 1023;
    int by = rem >> 5, bx = rem & 31;
    const float* W; unsigned short* Out;
    if      (z == 0) { W = Wq; Out = wqkvt; }
    else if (z == 1) { W = Wk; Out = wqkvt + (size_t)DD * DD; }
    else if (z == 2) { W = Wv; Out = wqkvt + 2 * (size_t)DD * DD; }
    else             { W = Wo; Out = wot; }
    int d0 = by * 64, f0 = bx * 64;
    int rr = t >> 4, c4 = (t & 15) * 4;
#pragma unroll
    for (int i = 0; i < 4; i++) {
      int row = rr + i * 16;
      float4 v = *(const float4*)&W[(size_t)(d0 + row) * DD + f0 + c4];
      tile[row][c4] = v.x; tile[row][c4 + 1] = v.y;
      tile[row][c4 + 2] = v.z; tile[row][c4 + 3] = v.w;
    }
    __syncthreads();
#pragma unroll
    for (int i = 0; i < 4; i++) {
      int f = rr + i * 16;
      ushort4 o4;
      o4.x = f2bf(tile[c4][f]);     o4.y = f2bf(tile[c4 + 1][f]);
      o4.z = f2bf(tile[c4 + 2][f]); o4.w = f2bf(tile[c4 + 3][f]);
      *(ushort4*)&Out[(size_t)(f0 + f) * DD + d0 + c4] = o4;
    }
  } else if (bid < 4096 + 8192) {
    // x -> bf16
    size_t i = ((size_t)(bid - 4096) * 256 + t) * 4;
    float4 v = *(const float4*)(x + i);
    ushort4 o;
    o.x = f2bf(v.x); o.y = f2bf(v.y); o.z = f2bf(v.z); o.w = f2bf(v.w);
    *(ushort4*)(xb + i) = o;
  } else {
    // RoPE cos/sin table: rtab[s][c] = (cos, sin), s<2048, c<64
    int idx = (bid - 12288) * 256 + t;
    int s = idx >> 6, c = idx & 63;
    float inv = powf(10000.f, -(float)c * (1.f / 64.f));
    float ang = (float)s * inv;
    float sn, cc;
    sincosf(ang, &sn, &cc);
    rtab[idx] = make_float2(cc, sn);
  }
}

// ---------------- fused QKV GEMM + bias + RoPE + V-transpose (proven 123 µs) ----
// C[4096,6144] = xb * wqkvt^T. 128x128 tile == exactly one (plane, head) column
// block. Epilogue round-trips the tile through LDS (stride 132 = +4 pad) and
// writes q_r/k_r (bias+RoPE, q prescaled by 1/sqrt(HD)*log2e) or v_t
// (bias + [hd][s] transpose with kappa key-permute) directly.
__global__ __launch_bounds__(256) void gemm_qkv(
    const unsigned short* __restrict__ A, const unsigned short* __restrict__ Bt,
    const float* __restrict__ bq, const float* __restrict__ bk,
    const float* __restrict__ bv, const float2* __restrict__ rtab,
    unsigned short* __restrict__ q_r, unsigned short* __restrict__ k_r,
    unsigned short* __restrict__ v_t)
{
  __shared__ unsigned short smem[16896];   // As(8192)|Bs(8192); reused as Ct[128][132]
  unsigned short* As = smem;
  unsigned short* Bs = smem + 8192;
  const int K = DD;
  int t = threadIdx.x;
  int m0 = blockIdx.y * 128, n0 = blockIdx.x * 128;
  int w = t >> 6, lane = t & 63, qd = lane >> 4, l16 = lane & 15;
  int wm = (w >> 1) * 64, wn = (w & 1) * 64;
  floatx4 zero4 = {0.f, 0.f, 0.f, 0.f};
  floatx4 acc[4][4];
#pragma unroll
  for (int i = 0; i < 4; i++)
#pragma unroll
    for (int j = 0; j < 4; j++) acc[i][j] = zero4;

  int gchunk = (t & 7) ^ ((t >> 3) & 7);
  const unsigned short* Ab = A  + (size_t)(m0 + (t >> 3)) * K + gchunk * 8;
  const unsigned short* Bb = Bt + (size_t)(n0 + (t >> 3)) * K + gchunk * 8;
  size_t qK = (size_t)32 * K;

  for (int k0 = 0; k0 < K; k0 += 64) {
    __syncthreads();
#pragma unroll
    for (int c = 0; c < 4; c++) {
      gl_lds16(Ab + c * qK + k0, &As[(c * 256 + t) * 8]);
      gl_lds16(Bb + c * qK + k0, &Bs[(c * 256 + t) * 8]);
    }
    __syncthreads();
#pragma unroll
    for (int ks = 0; ks < 2; ks++) {
      int ch = ((ks * 4 + qd) ^ (l16 & 7)) * 8;
      short8 af[4], bfr[4];
#pragma unroll
      for (int i = 0; i < 4; i++)
        af[i] = *(const short8*)&As[(wm + i * 16 + l16) * 64 + ch];
#pragma unroll
      for (int j = 0; j < 4; j++)
        bfr[j] = *(const short8*)&Bs[(wn + j * 16 + l16) * 64 + ch];
#pragma unroll
      for (int i = 0; i < 4; i++)
#pragma unroll
        for (int j = 0; j < 4; j++)
          acc[i][j] = __builtin_amdgcn_mfma_f32_16x16x32_bf16(af[i], bfr[j], acc[i][j], 0, 0, 0);
    }
  }

  // ---- epilogue ----
  int plane = n0 >> 11;            // 0=q, 1=k, 2=v
  int h = (n0 >> 7) & 15;
  const float* bias = plane == 0 ? bq : (plane == 1 ? bk : bv);
  __syncthreads();                 // all waves done reading As/Bs
#pragma unroll
  for (int i = 0; i < 4; i++)
#pragma unroll
    for (int j = 0; j < 4; j++) {
      int rl = wm + i * 16 + qd * 4;
      int cl = wn + j * 16 + l16;
      float bsv = bias[h * 128 + cl];
#pragma unroll
      for (int r = 0; r < 4; r++)
        smem[(rl + r) * 132 + cl] = f2bf(acc[i][j][r] + bsv);
    }
  __syncthreads();

  int b = m0 >> 11, sbase = m0 & (SS - 1);
  if (plane < 2) {
    unsigned short* dst = (plane == 0 ? q_r : k_r) + (size_t)(b * HH + h) * SS * HDD;
    // q prescale: 1/sqrt(128) * log2(e); k unscaled
    const float fac = (plane == 0) ? 0.12751744f : 1.0f;
#pragma unroll
    for (int it = 0; it < 16; it++) {
      int idx = it * 256 + t;
      int rl = idx >> 5, c2 = (idx & 31) * 2;
      int s = sbase + rl;
      float4 cs = *(const float4*)&rtab[(size_t)s * 64 + c2]; // cos0,sin0,cos1,sin1
      float a0 = bf2f(smem[rl * 132 + c2]);
      float a1 = bf2f(smem[rl * 132 + c2 + 1]);
      float b0 = bf2f(smem[rl * 132 + c2 + 64]);
      float b1 = bf2f(smem[rl * 132 + c2 + 65]);
      unsigned int lo = pk2bf((a0 * cs.x - b0 * cs.y) * fac,
                              (a1 * cs.z - b1 * cs.w) * fac);
      unsigned int hi = pk2bf((a0 * cs.y + b0 * cs.x) * fac,
                              (a1 * cs.w + b1 * cs.z) * fac);
      size_t rowb = (size_t)s * HDD;
      *(unsigned int*)&dst[rowb + c2]      = lo;
      *(unsigned int*)&dst[rowb + c2 + 64] = hi;
    }
  } else {
    // v: transpose to [hd][s] with kappa key-permute within each 64-block
    unsigned short* dst = v_t + (size_t)(b * HH + h) * HDD * SS;
#pragma unroll
    for (int it = 0; it < 32; it++) {
      int idx = it * 256 + t;
      int hd = idx >> 6, sp = (idx & 63) * 2;
      unsigned short v0 = smem[sp * 132 + hd];
      unsigned short v1 = smem[(sp + 1) * 132 + hd];
      int y = sp & 63;
      int kap = ((y >> 5) & 1) * 32 + ((y >> 2) & 3) * 8 + ((y >> 4) & 1) * 4 + (y & 3);
      int sg = sbase + (sp & ~63) + kap;
      *(unsigned int*)&dst[(size_t)hd * SS + sg] = ((unsigned int)v1 << 16) | v0;
    }
  }
}

// ---------------- bf16 MFMA GEMM, B^T layout, BK=64 (final projection) -----------
template <bool OUTF32>
__global__ __launch_bounds__(256) void gemm_bt(
    const unsigned short* __restrict__ A, const unsigned short* __restrict__ Bt,
    const float* __restrict__ bias, void* __restrict__ Cout,
    int M, int N, int K)
{
  __shared__ unsigned short As[128 * 64];
  __shared__ unsigned short Bs[128 * 64];
  int t = threadIdx.x;
  int m0 = blockIdx.y * 128, n0 = blockIdx.x * 128;
  int w = t >> 6, lane = t & 63, qd = lane >> 4, l16 = lane & 15;
  int wm = (w >> 1) * 64, wn = (w & 1) * 64;
  floatx4 zero4 = {0.f, 0.f, 0.f, 0.f};
  floatx4 acc[4][4];
#pragma unroll
  for (int i = 0; i < 4; i++)
#pragma unroll
    for (int j = 0; j < 4; j++) acc[i][j] = zero4;

  int gchunk = (t & 7) ^ ((t >> 3) & 7);
  const unsigned short* Ab = A  + (size_t)(m0 + (t >> 3)) * K + gchunk * 8;
  const unsigned short* Bb = Bt + (size_t)(n0 + (t >> 3)) * K + gchunk * 8;
  size_t qK = (size_t)32 * K;

  for (int k0 = 0; k0 < K; k0 += 64) {
    __syncthreads();
#pragma unroll
    for (int c = 0; c < 4; c++) {
      gl_lds16(Ab + c * qK + k0, &As[(c * 256 + t) * 8]);
      gl_lds16(Bb + c * qK + k0, &Bs[(c * 256 + t) * 8]);
    }
    __syncthreads();
#pragma unroll
    for (int ks = 0; ks < 2; ks++) {
      int ch = ((ks * 4 + qd) ^ (l16 & 7)) * 8;
      short8 af[4], bfr[4];
#pragma unroll
      for (int i = 0; i < 4; i++)
        af[i] = *(const short8*)&As[(wm + i * 16 + l16) * 64 + ch];
#pragma unroll
      for (int j = 0; j < 4; j++)
        bfr[j] = *(const short8*)&Bs[(wn + j * 16 + l16) * 64 + ch];
#pragma unroll
      for (int i = 0; i < 4; i++)
#pragma unroll
        for (int j = 0; j < 4; j++)
          acc[i][j] = __builtin_amdgcn_mfma_f32_16x16x32_bf16(af[i], bfr[j], acc[i][j], 0, 0, 0);
    }
  }

#pragma unroll
  for (int i = 0; i < 4; i++)
#pragma unroll
    for (int j = 0; j < 4; j++) {
      int row = m0 + wm + i * 16 + qd * 4;
      int col = n0 + wn + j * 16 + l16;
      float bsv = bias ? bias[col] : 0.f;
#pragma unroll
      for (int r = 0; r < 4; r++) {
        float v = acc[i][j][r] + bsv;
        if (OUTF32) ((float*)Cout)[(size_t)(row + r) * N + col] = v;
        else ((unsigned short*)Cout)[(size_t)(row + r) * N + col] = f2bf(v);
      }
    }
}

// ---------------- flash attention v7: dbuf LDS staging + setprio + defer-max ----
// Scores arrive in log2 domain (q pre-scaled by 1/sqrt(HD)*log2e), so softmax
// uses native v_exp_f32 (2^x). Defer-max (T13, THR=8 in log2 domain): skip the
// O/l rescale while rmax <= m_i + 8; P is then bounded by 2^8, harmless in
// bf16, and O,l stay consistently scaled by 2^-m_i (math exact).
__global__ __launch_bounds__(256, 2) void attn_kernel(
    const unsigned short* __restrict__ q_r, const unsigned short* __restrict__ k_r,
    const unsigned short* __restrict__ v_t, unsigned short* __restrict__ aout)
{
  __shared__ unsigned short Ks[2][64 * 128];   // [key][hd], swizzled chunks
  __shared__ unsigned short Vs[2][128 * 64];   // [hd][key-slot], swizzled chunks
  int t = threadIdx.x, w = t >> 6, lane = t & 63, qd = lane >> 4, l16 = lane & 15;
  // XCD-aware remap: all 16 q-tiles of one head land on one XCD
  int L = blockIdx.y * gridDim.x + blockIdx.x;
  int jj = L >> 3;
  int bh = (L & 7) * 4 + (jj >> 4);
  int q0 = (jj & 15) * 128;
  const unsigned short* qb = q_r + (size_t)bh * SS * HDD;
  const unsigned short* kb = k_r + (size_t)bh * SS * HDD;
  const unsigned short* vb = v_t + (size_t)bh * HDD * SS;

  short8 aq[2][4];
#pragma unroll
  for (int mi = 0; mi < 2; mi++)
#pragma unroll
    for (int ks = 0; ks < 4; ks++)
      aq[mi][ks] = *(const short8*)
          &qb[(size_t)(q0 + w * 32 + mi * 16 + l16) * HDD + ks * 32 + qd * 8];

  float m_i[2], l_i[2];
  floatx4 zero4 = {0.f, 0.f, 0.f, 0.f};
  floatx4 o[2][8];   // O^T: rows hd (8 blocks of 16), cols qrow (mi)
#pragma unroll
  for (int mi = 0; mi < 2; mi++) { m_i[mi] = -1e30f; l_i[mi] = 0.f; }
#pragma unroll
  for (int mi = 0; mi < 2; mi++)
#pragma unroll
    for (int n = 0; n < 8; n++) o[mi][n] = zero4;

  auto stage = [&](int nb, int kt) {
#pragma unroll
    for (int c = 0; c < 4; c++) {       // K tile: 64 rows x 128 elems
      int flat = c * 256 + t;
      int r = flat >> 4, cc = flat & 15;
      gl_lds16(kb + (size_t)(kt + r) * HDD + (cc ^ (r & 15)) * 8, &Ks[nb][flat * 8]);
    }
#pragma unroll
    for (int c = 0; c < 4; c++) {       // V^T tile: 128 rows x 64 slots
      int flat = c * 256 + t;
      int r = flat >> 3, cc = flat & 7;
      gl_lds16(vb + (size_t)r * SS + kt + (cc ^ (r & 7)) * 8, &Vs[nb][flat * 8]);
    }
  };

  stage(0, 0);
  int buf = 0;

  for (int kt = 0; kt < SS; kt += 64) {
    __syncthreads();                     // drains staging of `buf`
    if (kt + 64 < SS) stage(buf ^ 1, kt + 64);   // prefetch next tile

    floatx4 sc[2][4];
#pragma unroll
    for (int mi = 0; mi < 2; mi++)
#pragma unroll
      for (int j = 0; j < 4; j++) sc[mi][j] = zero4;
    __builtin_amdgcn_s_setprio(1);
#pragma unroll
    for (int j = 0; j < 4; j++) {
      int krow = j * 16 + l16;
#pragma unroll
      for (int ks = 0; ks < 4; ks++) {
        int chunk = ks * 4 + qd;
        short8 kf = *(const short8*)&Ks[buf][krow * 128 + ((chunk ^ (krow & 15)) * 8)];
        sc[0][j] = __builtin_amdgcn_mfma_f32_16x16x32_bf16(kf, aq[0][ks], sc[0][j], 0, 0, 0);
        sc[1][j] = __builtin_amdgcn_mfma_f32_16x16x32_bf16(kf, aq[1][ks], sc[1][j], 0, 0, 0);
      }
    }
    __builtin_amdgcn_s_setprio(0);

    float rmax[2];
#pragma unroll
    for (int mi = 0; mi < 2; mi++) {
      float m = sc[mi][0][0];
#pragma unroll
      for (int j = 0; j < 4; j++)
#pragma unroll
        for (int r = 0; r < 4; r++) m = fmaxf(m, sc[mi][j][r]);
      m = fmaxf(m, __shfl_xor(m, 16, 64));
      m = fmaxf(m, __shfl_xor(m, 32, 64));
      rmax[mi] = m;
    }

    // defer-max: rescale only when a row's max exceeds the running max by >8
    // (log2 domain -> P bounded by 2^8 = 256, exact math either way)
    bool up = (rmax[0] > m_i[0] + 8.f) || (rmax[1] > m_i[1] + 8.f);
    if (__ballot(up) != 0ull) {
#pragma unroll
      for (int mi = 0; mi < 2; mi++) {
        float mn = fmaxf(m_i[mi], rmax[mi]);
        float a = fexp2(m_i[mi] - mn);
        m_i[mi] = mn;
        l_i[mi] *= a;
#pragma unroll
        for (int n = 0; n < 8; n++)
#pragma unroll
          for (int r = 0; r < 4; r++) o[mi][n][r] *= a;
      }
    }

    unsigned int pr[2][4][2];
#pragma unroll
    for (int mi = 0; mi < 2; mi++) {
      float s0 = 0.f;
#pragma unroll
      for (int j = 0; j < 4; j++) {
        float p0 = fexp2(sc[mi][j][0] - m_i[mi]);
        float p1 = fexp2(sc[mi][j][1] - m_i[mi]);
        float p2 = fexp2(sc[mi][j][2] - m_i[mi]);
        float p3 = fexp2(sc[mi][j][3] - m_i[mi]);
        s0 += (p0 + p1) + (p2 + p3);
        pr[mi][j][0] = pk2bf(p0, p1);
        pr[mi][j][1] = pk2bf(p2, p3);
      }
      s0 += __shfl_xor(s0, 16, 64);
      s0 += __shfl_xor(s0, 32, 64);
      l_i[mi] += s0;
    }

    __builtin_amdgcn_s_setprio(1);
#pragma unroll
    for (int n = 0; n < 8; n++) {
      int vrow = n * 16 + l16;
#pragma unroll
      for (int ks = 0; ks < 2; ks++) {
        int chunk = ks * 4 + qd;
        short8 av = *(const short8*)&Vs[buf][vrow * 64 + ((chunk ^ (vrow & 7)) * 8)];
        union { unsigned int u[4]; short8 v; } bp0, bp1;
        bp0.u[0] = pr[0][2 * ks][0];     bp0.u[1] = pr[0][2 * ks][1];
        bp0.u[2] = pr[0][2 * ks + 1][0]; bp0.u[3] = pr[0][2 * ks + 1][1];
        bp1.u[0] = pr[1][2 * ks][0];     bp1.u[1] = pr[1][2 * ks][1];
        bp1.u[2] = pr[1][2 * ks + 1][0]; bp1.u[3] = pr[1][2 * ks + 1][1];
        o[0][n] = __builtin_amdgcn_mfma_f32_16x16x32_bf16(av, bp0.v, o[0][n], 0, 0, 0);
        o[1][n] = __builtin_amdgcn_mfma_f32_16x16x32_bf16(av, bp1.v, o[1][n], 0, 0, 0);
      }
    }
    __builtin_amdgcn_s_setprio(0);
    buf ^= 1;
  }

  int b = bh >> 4, h = bh & 15;
#pragma unroll
  for (int mi = 0; mi < 2; mi++) {
    int qrow = q0 + w * 32 + mi * 16 + l16;
    float inv_l = 1.f / l_i[mi];
    size_t base = ((size_t)(b * SS + qrow)) * DD + h * HDD;
#pragma unroll
    for (int n = 0; n < 8; n++) {
      uint2 pkd;
      pkd.x = pk2bf(o[mi][n][0] * inv_l, o[mi][n][1] * inv_l);
      pkd.y = pk2bf(o[mi][n][2] * inv_l, o[mi][n][3] * inv_l);
      *(uint2*)&aout[base + n * 16 + qd * 4] = pkd;
    }
  }
}

// ---------------- launch ----------------
extern "C" void kernel_launch(void* const* d_in, const int* in_sizes, int n_in,
                              void* d_out, int out_size, void* d_ws, size_t ws_size,
                              hipStream_t stream) {
  const float* x  = (const float*)d_in[0];
  const float* Wq = (const float*)d_in[1];
  const float* bq = (const float*)d_in[2];
  const float* Wk = (const float*)d_in[3];
  const float* bk = (const float*)d_in[4];
  const float* Wv = (const float*)d_in[5];
  const float* bv = (const float*)d_in[6];
  const float* Wo = (const float*)d_in[7];
  const float* bo = (const float*)d_in[8];
  float* out = (float*)d_out;

  char* ws = (char*)d_ws;
  unsigned short* xb      = (unsigned short*)(ws + 0);            // [BS,D] bf16, 16 MB
  unsigned short* wqkvt   = (unsigned short*)(ws + 16777216);     // [3D,D] bf16, 24 MB
  unsigned short* wot     = (unsigned short*)(ws + 41943040);     // [D,D]  bf16, 8 MB
  float2*         rtab    = (float2*)(ws + 50331648);             // [S,64] f32x2, 1 MB
  unsigned short* q_r     = (unsigned short*)(ws + 100663296);    // [B,H,S,HD] 16 MB
  unsigned short* k_r     = (unsigned short*)(ws + 117440512);    // [B,H,S,HD] 16 MB
  unsigned short* v_t     = (unsigned short*)(ws + 134217728);    // [B,H,HD,S] 16 MB
  unsigned short* attn_o  = xb;   // alias: xb dead after gemm_qkv

  prep<<<dim3(12800), dim3(256), 0, stream>>>(
      x, Wq, Wk, Wv, Wo, xb, wqkvt, wot, rtab);
  gemm_qkv<<<dim3(3 * DD / 128, BSR / 128), dim3(256), 0, stream>>>(
      xb, wqkvt, bq, bk, bv, rtab, q_r, k_r, v_t);
  attn_kernel<<<dim3(SS / 128, BB * HH), dim3(256), 0, stream>>>(
      q_r, k_r, v_t, attn_o);
  gemm_bt<true><<<dim3(DD / 128, BSR / 128), dim3(256), 0, stream>>>(
      attn_o, wot, bo, out, BSR, DD, DD);
}